// Round 1
// baseline (1770.924 us; speedup 1.0000x reference)
//
#include <hip/hip_runtime.h>
#include <math.h>

typedef unsigned long long u64;
typedef unsigned int u32;

#define Hh 960
#define Ww 1280
#define Bb 2
#define Kk 1024
#define Pp 256
#define KP1 1025
#define NSEG 4
#define LISTCAP 131072

static const size_t HWp = (size_t)Hh * Ww;   // one plane
static const size_t PLn = HWp * Bb;          // B planes

#define TAUf 0.2f
#define NMS_EPS 1e-7f
#define DET_T 0.001f
#define NORMV (-7.6246189861593985f)   /* -log(2*K) */
#define LOGKV (6.9314718055994531f)    /* log(K) */

__constant__ float WR[6] = {1.0f, 1.0f/9.0f, 1.0f/25.0f, 1.0f/49.0f, 1.0f/81.0f, 1.0f/121.0f};

__device__ __forceinline__ int imin(int a,int b){return a<b?a:b;}
__device__ __forceinline__ int imax(int a,int b){return a>b?a:b;}

// ---------------- FED diffusion step (fused: Sobel->g->flux) ----------------
__global__ __launch_bounds__(256) void fed_step(const float* __restrict__ src, float* __restrict__ dst){
  __shared__ float Lt[36][37];
  __shared__ float Gt[34][35];
  const int bx = blockIdx.x*32, by = blockIdx.y*32, b = blockIdx.z;
  const float* S = src + (size_t)b*HWp;
  float* D = dst + (size_t)b*HWp;
  const int t = threadIdx.y*32 + threadIdx.x;
  for (int i=t;i<36*36;i+=256){
    int ly=i/36, lx=i-ly*36;
    int gy=by+ly-2, gx=bx+lx-2;
    Lt[ly][lx] = (gy>=0 && gy<Hh && gx>=0 && gx<Ww) ? S[(size_t)gy*Ww+gx] : 0.0f;  // zero-pad for Sobel
  }
  __syncthreads();
  const float k2 = (float)(0.05*0.05);
  for (int i=t;i<34*34;i+=256){
    int ly=i/34, lx=i-ly*34;
    int Ly=ly+1, Lx=lx+1;
    float sx = (-Lt[Ly-1][Lx-1]+Lt[Ly-1][Lx+1]
                -2.0f*Lt[Ly][Lx-1]+2.0f*Lt[Ly][Lx+1]
                -Lt[Ly+1][Lx-1]+Lt[Ly+1][Lx+1])*0.125f;
    float sy = (-Lt[Ly-1][Lx-1]-2.0f*Lt[Ly-1][Lx]-Lt[Ly-1][Lx+1]
                +Lt[Ly+1][Lx-1]+2.0f*Lt[Ly+1][Lx]+Lt[Ly+1][Lx+1])*0.125f;
    Gt[ly][lx] = 1.0f/(1.0f + (sx*sx+sy*sy)/k2);
  }
  __syncthreads();
  for (int r=0;r<4;++r){
    int oy=threadIdx.y + r*8, ox=threadIdx.x;
    int gy=by+oy, gx=bx+ox;
    if (gy>=Hh || gx>=Ww) continue;
    // edge-clamped neighbor coordinates (matches np.pad 'edge')
    int gyn=imax(gy-1,0), gys=imin(gy+1,Hh-1), gxw=imax(gx-1,0), gxe=imin(gx+1,Ww-1);
    float Lc=Lt[oy+2][ox+2];
    float Ln=Lt[gyn-by+2][ox+2];
    float Ls=Lt[gys-by+2][ox+2];
    float Lw=Lt[oy+2][gxw-bx+2];
    float Le=Lt[oy+2][gxe-bx+2];
    float gc=Gt[oy+1][ox+1];
    float gn=Gt[gyn-by+1][ox+1];
    float gs=Gt[gys-by+1][ox+1];
    float gw=Gt[oy+1][gxw-bx+1];
    float ge=Gt[oy+1][gxe-bx+1];
    float flux = 0.5f*((gc+gn)*(Ln-Lc) + (gc+gs)*(Ls-Lc) + (gc+gw)*(Lw-Lc) + (gc+ge)*(Le-Lc));
    D[(size_t)gy*Ww+gx] = Lc + TAUf*flux;
  }
}

// ---------------- Hessian response (Lxx*Lyy - Lxy^2), resp = max(resp, det) ----------------
__global__ __launch_bounds__(256) void response_kernel(const float* __restrict__ src, float* __restrict__ resp){
  __shared__ float Lt[36][37];
  __shared__ float Sx[34][35];
  const int bx = blockIdx.x*32, by = blockIdx.y*32, b = blockIdx.z;
  const float* S = src + (size_t)b*HWp;
  float* R = resp + (size_t)b*HWp;
  const int t = threadIdx.y*32 + threadIdx.x;
  for (int i=t;i<36*36;i+=256){
    int ly=i/36, lx=i-ly*36;
    int gy=by+ly-2, gx=bx+lx-2;
    Lt[ly][lx] = (gy>=0 && gy<Hh && gx>=0 && gx<Ww) ? S[(size_t)gy*Ww+gx] : 0.0f;
  }
  __syncthreads();
  for (int i=t;i<34*34;i+=256){
    int ly=i/34, lx=i-ly*34;
    int gy=by+ly-1, gx=bx+lx-1;
    float v=0.0f;
    if (gy>=0 && gy<Hh && gx>=0 && gx<Ww){   // Sx is zero outside image (zero-pad of first conv's output)
      int Ly=ly+1, Lx=lx+1;
      v = (-Lt[Ly-1][Lx-1]+Lt[Ly-1][Lx+1]
           -2.0f*Lt[Ly][Lx-1]+2.0f*Lt[Ly][Lx+1]
           -Lt[Ly+1][Lx-1]+Lt[Ly+1][Lx+1])*0.125f;
    }
    Sx[ly][lx]=v;
  }
  __syncthreads();
  for (int r=0;r<4;++r){
    int oy=threadIdx.y + r*8, ox=threadIdx.x;
    int gy=by+oy, gx=bx+ox;
    if (gy>=Hh || gx>=Ww) continue;
    int Ly=oy+2, Lx=ox+2;
    float Lxx = Lt[Ly][Lx-1]-2.0f*Lt[Ly][Lx]+Lt[Ly][Lx+1];
    float Lyy = Lt[Ly-1][Lx]-2.0f*Lt[Ly][Lx]+Lt[Ly+1][Lx];
    int Sy=oy+1, Sxi=ox+1;
    float Lxy = (-Sx[Sy-1][Sxi-1]-2.0f*Sx[Sy-1][Sxi]-Sx[Sy-1][Sxi+1]
                 +Sx[Sy+1][Sxi-1]+2.0f*Sx[Sy+1][Sxi]+Sx[Sy+1][Sxi+1])*0.125f;
    float det = Lxx*Lyy - Lxy*Lxy;
    size_t id=(size_t)gy*Ww+gx;
    R[id] = fmaxf(R[id], det);
  }
}

// ---------------- threshold ----------------
__global__ void thresh_kernel(const float* __restrict__ in, float* __restrict__ outp, size_t n){
  size_t i=(size_t)blockIdx.x*256+threadIdx.x;
  if(i<n){ float v=in[i]; outp[i]=(v>DET_T)?v:0.0f; }
}

// ---------------- maxpool-NMS mask (radius R) ----------------
template<int R>
__global__ __launch_bounds__(256) void nms_mask_kernel(const float* __restrict__ in, float* __restrict__ outp){
  constexpr int TS=32+2*R;
  __shared__ float Lt[TS][TS+1];
  const int bx = blockIdx.x*32, by = blockIdx.y*32, b = blockIdx.z;
  const float* S = in + (size_t)b*HWp;
  float* D = outp + (size_t)b*HWp;
  const int t = threadIdx.y*32 + threadIdx.x;
  for (int i=t;i<TS*TS;i+=256){
    int ly=i/TS, lx=i-ly*TS;
    int gy=by+ly-R, gx=bx+lx-R;
    Lt[ly][lx] = (gy>=0 && gy<Hh && gx>=0 && gx<Ww) ? S[(size_t)gy*Ww+gx] : 0.0f; // map >=0 so 0-pad == clipped window
  }
  __syncthreads();
  for (int r=0;r<4;++r){
    int oy=threadIdx.y + r*8, ox=threadIdx.x;
    int gy=by+oy, gx=bx+ox;
    if (gy>=Hh || gx>=Ww) continue;
    float m=0.0f;
    #pragma unroll
    for(int dy=0;dy<2*R+1;dy++)
      #pragma unroll
      for(int dx=0;dx<2*R+1;dx++)
        m=fmaxf(m,Lt[oy+dy][ox+dx]);
    float v=Lt[oy+R][ox+R];
    D[(size_t)gy*Ww+gx]=(v>=m-NMS_EPS)?v:0.0f;
  }
}

// ---------------- 7x7 NMS + compact positives to (value,~idx) keys ----------------
__global__ __launch_bounds__(256) void nms7_compact(const float* __restrict__ in, u64* __restrict__ lists,
                                                    int* __restrict__ cnt, int segbase){
  constexpr int R=3, TS=38;
  __shared__ float Lt[TS][TS+1];
  const int bx = blockIdx.x*32, by = blockIdx.y*32, b = blockIdx.z;
  const float* S = in + (size_t)b*HWp;
  const int t = threadIdx.y*32 + threadIdx.x;
  for (int i=t;i<TS*TS;i+=256){
    int ly=i/TS, lx=i-ly*TS;
    int gy=by+ly-R, gx=bx+lx-R;
    Lt[ly][lx] = (gy>=0 && gy<Hh && gx>=0 && gx<Ww) ? S[(size_t)gy*Ww+gx] : 0.0f;
  }
  __syncthreads();
  int seg=segbase+b;
  for (int r=0;r<4;++r){
    int oy=threadIdx.y + r*8, ox=threadIdx.x;
    int gy=by+oy, gx=bx+ox;
    if (gy>=Hh || gx>=Ww) continue;
    float v=Lt[oy+R][ox+R];
    if (v<=0.0f) continue;
    float m=0.0f;
    #pragma unroll
    for(int dy=0;dy<7;dy++)
      #pragma unroll
      for(int dx=0;dx<7;dx++)
        m=fmaxf(m,Lt[oy+dy][ox+dx]);
    if (v>=m-NMS_EPS){
      u32 idx=(u32)(gy*Ww+gx);
      u64 key=((u64)__float_as_uint(v)<<32)|(u64)(0xFFFFFFFFu-idx);  // value desc, index asc
      int pos=atomicAdd(&cnt[seg],1);
      if(pos<LISTCAP) lists[(size_t)seg*LISTCAP+pos]=key;
    }
  }
}

// ---------------- radix-select top-K: histogram pass ----------------
__global__ void topk_hist(const u64* __restrict__ lists, const int* __restrict__ cnt,
                          const u64* __restrict__ prefix, const int* __restrict__ takeAll,
                          u32* __restrict__ ghist, int round){
  int seg=blockIdx.y;
  if(round>0 && takeAll[seg]) return;
  __shared__ u32 h[256];
  h[threadIdx.x]=0; __syncthreads();
  int n=imin(cnt[seg],LISTCAP);
  int shift=56-8*round;
  u64 maskHi=(round==0)?0ULL:(~0ULL<<(shift+8));
  u64 pfx=prefix[seg];
  for(int i=blockIdx.x*256+threadIdx.x;i<n;i+=gridDim.x*256){
    u64 k=lists[(size_t)seg*LISTCAP+i];
    if((k&maskHi)==pfx) atomicAdd(&h[(int)((k>>shift)&255ULL)],1u);
  }
  __syncthreads();
  if(h[threadIdx.x]) atomicAdd(&ghist[seg*256+threadIdx.x],h[threadIdx.x]);
}

// ---------------- radix-select: decide byte, advance state ----------------
__global__ void topk_decide(u32* __restrict__ ghist, const int* __restrict__ cnt,
                            int* __restrict__ krem, int* __restrict__ takeAll,
                            u64* __restrict__ prefix, u64* __restrict__ Tf, int round){
  int t=threadIdx.x;
  if(t<NSEG){
    int seg=t;
    if(round==0){
      krem[seg]=Kk;
      prefix[seg]=0ULL;
      takeAll[seg]=(imin(cnt[seg],LISTCAP)<=Kk)?1:0;
    }
    if(takeAll[seg]){
      if(round==7) Tf[seg]=1ULL;   // all keys >= 1 (value>0 => high bits nonzero)
    } else {
      int kr=krem[seg];
      const u32* h=&ghist[seg*256];
      int acc=0; int b=255;
      for(;b>0;--b){ int c2=(int)h[b]; if(acc+c2>=kr) break; acc+=c2; }
      int shift=56-8*round;
      prefix[seg]|=((u64)(u32)b)<<shift;
      krem[seg]=kr-acc;
      if(round==7) Tf[seg]=prefix[seg];
    }
  }
  __syncthreads();
  for(int i=t;i<NSEG*256;i+=blockDim.x) ghist[i]=0u;  // clear for next round
}

// ---------------- gather keys >= threshold ----------------
__global__ void topk_gather(const u64* __restrict__ lists, const int* __restrict__ cnt,
                            const u64* __restrict__ Tf, u64* __restrict__ selbuf, int* __restrict__ selcnt){
  int seg=blockIdx.y;
  int n=imin(cnt[seg],LISTCAP);
  u64 T=Tf[seg];
  for(int i=blockIdx.x*256+threadIdx.x;i<n;i+=gridDim.x*256){
    u64 k=lists[(size_t)seg*LISTCAP+i];
    if(k>=T){ int pos=atomicAdd(&selcnt[seg],1); if(pos<Kk) selbuf[(size_t)seg*Kk+pos]=k; }
  }
}

// ---------------- sort 1024 keys desc, emit keypoint meta + k1/k2 ----------------
__global__ __launch_bounds__(1024) void finalize_kernel(const u64* __restrict__ selbuf, const int* __restrict__ selcnt,
                                int* __restrict__ kyi, int* __restrict__ kxi, float* __restrict__ kval,
                                float* __restrict__ outp){
  int seg=blockIdx.x, tid=threadIdx.x;
  __shared__ u64 a[1024];
  int n=selcnt[seg]; if(n>Kk)n=Kk;
  a[tid]=(tid<n)?selbuf[(size_t)seg*Kk+tid]:0ULL;
  __syncthreads();
  for(int k=2;k<=1024;k<<=1){
    for(int j=k>>1;j>0;j>>=1){
      int ixj=tid^j;
      if(ixj>tid){
        u64 x=a[tid], y=a[ixj];
        bool desc=((tid&k)==0);
        if(desc ? (x<y) : (x>y)){ a[tid]=y; a[ixj]=x; }
      }
      __syncthreads();
    }
  }
  u64 key=a[tid];
  bool val=(key!=0ULL);
  u32 idx=0xFFFFFFFFu-(u32)(key&0xFFFFFFFFULL);
  int y= val ? (int)(idx/Ww) : 0;
  int x= val ? (int)(idx%Ww) : 0;
  int mi=seg*Kk+tid;
  kyi[mi]=y; kxi[mi]=x; kval[mi]= val?1.0f:0.0f;
  int imi=seg>>1, bb=seg&1;
  float* ko=outp + (size_t)imi*(Bb*Kk*2) + ((size_t)bb*Kk+tid)*2;
  ko[0]= val ? (float)y : -1.0f;
  ko[1]= val ? (float)x : -1.0f;
}

// ---------------- Gaussian weights (1D, normalized) ----------------
__global__ void init_weights(float* wn){
  if(threadIdx.x==0 && blockIdx.x==0){
    double w[15]; double S=0.0;
    for(int i=0;i<15;i++){ double c=(double)i-7.0; w[i]=exp(-(c*c)/(2.0*2.5*2.5)); S+=w[i]; }
    for(int i=0;i<15;i++) wn[i]=(float)(w[i]/S);
  }
}

__device__ __forceinline__ float ldz(const float* __restrict__ img,int y,int x){
  return (y>=0&&y<Hh&&x>=0&&x<Ww)?img[(size_t)y*Ww+x]:0.0f;
}

// ---------------- per-keypoint orientation (15x15 Gaussian-weighted Sobel) ----------------
__global__ __launch_bounds__(64) void orient_kernel(const float* __restrict__ img1, const float* __restrict__ img2,
                              const int* __restrict__ kyi, const int* __restrict__ kxi,
                              const float* __restrict__ wn, float* __restrict__ kth){
  int seg=blockIdx.y, ki=blockIdx.x, lane=threadIdx.x;
  __shared__ float w15[15];
  if(lane<15) w15[lane]=wn[lane];
  __syncthreads();
  const float* img=(seg<2?img1:img2)+(size_t)(seg&1)*HWp;
  int mi=seg*Kk+ki;
  int yc=kyi[mi], xc=kxi[mi];
  float ax=0.0f, ay=0.0f;
  for(int tp=lane;tp<225;tp+=64){
    int du=tp/15-7, dv=tp-(tp/15)*15-7;
    int yy=yc+du, xx=xc+dv;
    if(yy<0||yy>=Hh||xx<0||xx>=Ww) continue;   // zero-pad of Sobel output
    float p00=ldz(img,yy-1,xx-1), p01=ldz(img,yy-1,xx), p02=ldz(img,yy-1,xx+1);
    float p10=ldz(img,yy,xx-1),                          p12=ldz(img,yy,xx+1);
    float p20=ldz(img,yy+1,xx-1), p21=ldz(img,yy+1,xx), p22=ldz(img,yy+1,xx+1);
    float sx=(-p00+p02-2.0f*p10+2.0f*p12-p20+p22)*0.125f;
    float sy=(-p00-2.0f*p01-p02+p20+2.0f*p21+p22)*0.125f;
    float wgt=w15[du+7]*w15[dv+7];
    ax=fmaf(wgt,sx,ax); ay=fmaf(wgt,sy,ay);
  }
  for(int o=32;o;o>>=1){ ax+=__shfl_down(ax,o); ay+=__shfl_down(ay,o); }
  if(lane==0) kth[mi]=atan2f(ay,ax);
}

// ---------------- BAD descriptor: box samples + normalize ----------------
__device__ __forceinline__ float boxsum(const float* __restrict__ img, float px, float py, int r){
  float rx=rintf(px), ry=rintf(py);   // round-half-even, then clip (matches jnp.round->clip)
  int xi=(int)fminf(fmaxf(rx,0.0f),(float)(Ww-1));
  int yi=(int)fminf(fmaxf(ry,0.0f),(float)(Hh-1));
  float acc=0.0f;
  for(int dy=-r;dy<=r;dy++){
    int y=yi+dy; if(y<0||y>=Hh) continue;
    const float* rowp=img+(size_t)y*Ww;
    for(int dx=-r;dx<=r;dx++){
      int x=xi+dx; if(x<0||x>=Ww) continue;
      acc+=rowp[x];
    }
  }
  return acc;
}

__global__ __launch_bounds__(256) void bad_kernel(const float* __restrict__ img1, const float* __restrict__ img2,
                           const float* __restrict__ offs, const float* __restrict__ thrv,
                           const int* __restrict__ rad,
                           const int* __restrict__ kyi, const int* __restrict__ kxi,
                           const float* __restrict__ kval, const float* __restrict__ kth,
                           float* __restrict__ d1, float* __restrict__ d2,
                           float* __restrict__ sq1, float* __restrict__ sq2){
  int seg=blockIdx.y, ki=blockIdx.x, p=threadIdx.x;
  const float* img=(seg<2?img1:img2)+(size_t)(seg&1)*HWp;
  int mi=seg*Kk+ki;
  float yc=(float)kyi[mi], xc=(float)kxi[mi];
  float th=kth[mi];
  float c=cosf(th), s=sinf(th);
  float ox1=offs[p*4+0], oy1=offs[p*4+1], ox2=offs[p*4+2], oy2=offs[p*4+3];
  int r=rad[p];
  float w=WR[r];
  float px1=xc+c*ox1-s*oy1, py1=yc+s*ox1+c*oy1;
  float px2=xc+c*ox2-s*oy2, py2=yc+s*ox2+c*oy2;
  float s1=boxsum(img,px1,py1,r)*w;
  float s2=boxsum(img,px2,py2,r)*w;
  float v=(s1-s2-thrv[p])*kval[mi];
  __shared__ float sm[4];
  __shared__ float nsh;
  float t=v*v;
  for(int o=32;o;o>>=1) t+=__shfl_down(t,o);
  if((p&63)==0) sm[p>>6]=t;
  __syncthreads();
  if(p==0) nsh=sqrtf(sm[0]+sm[1]+sm[2]+sm[3]);
  __syncthreads();
  float dv=v/(nsh+1e-8f);
  float* dd=(seg<2?d1:d2);
  dd[((size_t)(seg&1)*Kk+ki)*Pp+p]=dv;
  float t2=dv*dv;
  for(int o=32;o;o>>=1) t2+=__shfl_down(t2,o);
  __syncthreads();
  if((p&63)==0) sm[p>>6]=t2;
  __syncthreads();
  if(p==0){ float* sq=(seg<2?sq1:sq2); sq[(size_t)(seg&1)*Kk+ki]=sm[0]+sm[1]+sm[2]+sm[3]; }
}

// ---------------- pairwise distance -> Z (and transposed copy) ----------------
__global__ __launch_bounds__(256) void dist_kernel(const float* __restrict__ d1, const float* __restrict__ d2,
                            const float* __restrict__ sq1, const float* __restrict__ sq2,
                            float* __restrict__ Zm, float* __restrict__ Zt){
  int b=blockIdx.z;
  int i0=blockIdx.y*16, j0=blockIdx.x*16;
  int ty=threadIdx.y, tx=threadIdx.x;
  __shared__ float A[16][17], Bs[16][17], Ct[16][17];
  const float* D1=d1+(size_t)b*Kk*Pp;
  const float* D2=d2+(size_t)b*Kk*Pp;
  float acc=0.0f;
  for(int p0=0;p0<Pp;p0+=16){
    A[ty][tx]=D1[(size_t)(i0+ty)*Pp+p0+tx];
    Bs[ty][tx]=D2[(size_t)(j0+ty)*Pp+p0+tx];
    __syncthreads();
    #pragma unroll
    for(int kk=0;kk<16;kk++) acc=fmaf(A[ty][kk],Bs[tx][kk],acc);
    __syncthreads();
  }
  float dd=sq1[b*Kk+i0+ty]+sq2[b*Kk+j0+tx]-2.0f*acc;
  float dist=sqrtf(fmaxf(dd,0.0f)+1e-12f);
  Zm[((size_t)b*KP1+(i0+ty))*KP1+(j0+tx)]=-dist;
  Ct[ty][tx]=-dist;
  __syncthreads();
  Zt[((size_t)b*KP1+(j0+ty))*KP1+(i0+tx)]=Ct[tx][ty];
}

__global__ void zborder_kernel(float* __restrict__ Zm, float* __restrict__ Zt){
  int i=blockIdx.x*256+threadIdx.x;
  if(i>=Bb*KP1) return;
  int b=i/KP1, j=i-(i/KP1)*KP1;
  Zm[((size_t)b*KP1+j)*KP1+Kk]=1.0f;
  Zm[((size_t)b*KP1+Kk)*KP1+j]=1.0f;
  Zt[((size_t)b*KP1+j)*KP1+Kk]=1.0f;
  Zt[((size_t)b*KP1+Kk)*KP1+j]=1.0f;
}

// ---------------- Sinkhorn half-iteration: res = log_mu - lse_j(Z[i,:]+o[:]) ----------------
__global__ __launch_bounds__(256) void sink_lse(const float* __restrict__ Zm, const float* __restrict__ ov,
                                                float* __restrict__ res){
  int b=blockIdx.y, i=blockIdx.x;
  const float* row=Zm+((size_t)b*KP1+i)*KP1;
  const float* o=ov+(size_t)b*KP1;
  __shared__ float sm[4];
  __shared__ float Msh;
  int tid=threadIdx.x;
  float m=-3.0e38f;
  for(int j=tid;j<KP1;j+=256) m=fmaxf(m,row[j]+o[j]);
  for(int off2=32;off2;off2>>=1) m=fmaxf(m,__shfl_down(m,off2));
  if((tid&63)==0) sm[tid>>6]=m;
  __syncthreads();
  if(tid==0) Msh=fmaxf(fmaxf(sm[0],sm[1]),fmaxf(sm[2],sm[3]));
  __syncthreads();
  float M=Msh;
  float s=0.0f;
  for(int j=tid;j<KP1;j+=256) s+=expf(row[j]+o[j]-M);
  for(int off2=32;off2;off2>>=1) s+=__shfl_down(s,off2);
  __syncthreads();
  if((tid&63)==0) sm[tid>>6]=s;
  __syncthreads();
  if(tid==0){
    float S=sm[0]+sm[1]+sm[2]+sm[3];
    float lm=(i<Kk)?NORMV:(LOGKV+NORMV);
    res[(size_t)b*KP1+i]=lm-(M+logf(S));
  }
}

// ---------------- final probs = exp(Z+u+v-norm) ----------------
__global__ void probs_kernel(const float* __restrict__ Zm, const float* __restrict__ uu,
                             const float* __restrict__ vv, float* __restrict__ outp){
  size_t i=(size_t)blockIdx.x*256+threadIdx.x;
  const size_t tot=(size_t)Bb*KP1*KP1;
  if(i>=tot) return;
  size_t b=i/((size_t)KP1*KP1);
  size_t rem=i-b*(size_t)KP1*KP1;
  int rr=(int)(rem/KP1), cc=(int)(rem-(size_t)(rem/KP1)*KP1);
  outp[i]=expf(Zm[i]+uu[b*KP1+rr]+vv[b*KP1+cc]-NORMV);
}

extern "C" void kernel_launch(void* const* d_in, const int* in_sizes, int n_in,
                              void* d_out, int out_size, void* d_ws, size_t ws_size,
                              hipStream_t stream) {
  (void)in_sizes; (void)n_in; (void)out_size; (void)ws_size;
  const float* img1=(const float*)d_in[0];
  const float* img2=(const float*)d_in[1];
  const float* offs=(const float*)d_in[2];
  const float* thrv=(const float*)d_in[3];
  const int*   rad =(const int*)d_in[4];
  float* out=(float*)d_out;

  char* wp=(char*)d_ws;
  auto carve=[&](size_t bytes)->char*{ char* p=wp; wp += (bytes+255)&~(size_t)255; return p; };
  float* r0  =(float*)carve(PLn*4);            // L ping / Z
  float* r1  =(float*)carve(PLn*4);            // L pong / Zt
  float* resp=(float*)carve(PLn*4);
  u64*  lists=(u64*)carve((size_t)NSEG*LISTCAP*8);
  char* stateblk = carve(4352);
  int* cnt     =(int*)(stateblk+0);
  int* selcnt  =(int*)(stateblk+16);
  int* krem    =(int*)(stateblk+32);
  int* takeAll =(int*)(stateblk+48);
  u64* prefix  =(u64*)(stateblk+64);
  u64* Tf      =(u64*)(stateblk+96);
  u32* ghist   =(u32*)(stateblk+128);
  u64* selbuf  =(u64*)carve((size_t)NSEG*Kk*8);
  int* kyi     =(int*)carve((size_t)NSEG*Kk*4);
  int* kxi     =(int*)carve((size_t)NSEG*Kk*4);
  float* kval  =(float*)carve((size_t)NSEG*Kk*4);
  float* kth   =(float*)carve((size_t)NSEG*Kk*4);
  float* d1    =(float*)carve((size_t)Bb*Kk*Pp*4);
  float* d2    =(float*)carve((size_t)Bb*Kk*Pp*4);
  float* sq1   =(float*)carve((size_t)Bb*Kk*4);
  float* sq2   =(float*)carve((size_t)Bb*Kk*4);
  float* uvec  =(float*)carve((size_t)Bb*KP1*4);
  float* vvec  =(float*)carve((size_t)Bb*KP1*4);
  float* wn    =(float*)carve(64);

  hipMemsetAsync(stateblk, 0, 4352, stream);
  init_weights<<<1,32,0,stream>>>(wn);

  dim3 TG(Ww/32, Hh/32, Bb), TB(32,8);
  for(int im=0; im<2; ++im){
    const float* srcimg = (im==0)? img1 : img2;
    hipMemsetAsync(resp, 0, PLn*4, stream);
    hipMemcpyAsync(r0, srcimg, PLn*4, hipMemcpyDeviceToDevice, stream);
    float* cur=r0; float* oth=r1;
    for(int st=1; st<=9; ++st){
      fed_step<<<TG,TB,0,stream>>>(cur, oth);
      float* tp=cur; cur=oth; oth=tp;
      if(st%3==0) response_kernel<<<TG,TB,0,stream>>>(cur, resp);
    }
    // after 9 steps: cur==r1 (final L, dead), oth==r0 (dead)
    thresh_kernel<<<dim3((u32)((PLn+255)/256)),dim3(256),0,stream>>>(resp, oth, PLn);
    nms_mask_kernel<2><<<TG,TB,0,stream>>>(oth, cur);
    nms7_compact<<<TG,TB,0,stream>>>(cur, lists, cnt, im*2);
  }

  for(int rd=0; rd<8; ++rd){
    topk_hist<<<dim3(32,NSEG),dim3(256),0,stream>>>(lists, cnt, prefix, takeAll, ghist, rd);
    topk_decide<<<1,256,0,stream>>>(ghist, cnt, krem, takeAll, prefix, Tf, rd);
  }
  topk_gather<<<dim3(64,NSEG),dim3(256),0,stream>>>(lists, cnt, Tf, selbuf, selcnt);
  finalize_kernel<<<NSEG,1024,0,stream>>>(selbuf, selcnt, kyi, kxi, kval, out);
  orient_kernel<<<dim3(Kk,NSEG),dim3(64),0,stream>>>(img1, img2, kyi, kxi, wn, kth);
  bad_kernel<<<dim3(Kk,NSEG),dim3(256),0,stream>>>(img1, img2, offs, thrv, rad,
                                                   kyi, kxi, kval, kth, d1, d2, sq1, sq2);

  float* Zm=r0; float* Zt=r1;   // reuse image buffers
  dist_kernel<<<dim3(64,64,Bb),dim3(16,16),0,stream>>>(d1,d2,sq1,sq2,Zm,Zt);
  zborder_kernel<<<dim3((Bb*KP1+255)/256),dim3(256),0,stream>>>(Zm,Zt);
  hipMemsetAsync(uvec,0,(size_t)Bb*KP1*4,stream);
  hipMemsetAsync(vvec,0,(size_t)Bb*KP1*4,stream);
  for(int it=0; it<20; ++it){
    sink_lse<<<dim3(KP1,Bb),dim3(256),0,stream>>>(Zm, vvec, uvec);
    sink_lse<<<dim3(KP1,Bb),dim3(256),0,stream>>>(Zt, uvec, vvec);
  }
  size_t tot=(size_t)Bb*KP1*KP1;
  probs_kernel<<<dim3((u32)((tot+255)/256)),dim3(256),0,stream>>>(Zm, uvec, vvec, out + (size_t)2*Bb*Kk*2);
}

// Round 2
// 1059.490 us; speedup vs baseline: 1.6715x; 1.6715x over previous
//
#include <hip/hip_runtime.h>
#include <math.h>

typedef unsigned long long u64;
typedef unsigned int u32;

#define Hh 960
#define Ww 1280
#define Bb 2
#define Kk 1024
#define Pp 256
#define KP1 1025
#define NSEG 4
#define LISTCAP 131072

static const size_t HWp = (size_t)Hh * Ww;   // one plane
static const size_t PLn = HWp * Bb;          // B planes

#define TAUf 0.2f
#define NMS_EPS 1e-7f
#define DET_T 0.001f
#define NORMV (-7.6246189861593985f)   /* -log(2*K) */
#define LOGKV (6.9314718055994531f)    /* log(K) */

__constant__ float WR[6] = {1.0f, 1.0f/9.0f, 1.0f/25.0f, 1.0f/49.0f, 1.0f/81.0f, 1.0f/121.0f};

__device__ __forceinline__ int imin(int a,int b){return a<b?a:b;}
__device__ __forceinline__ int imax(int a,int b){return a>b?a:b;}

// ---------------- FED diffusion step (fused: Sobel->g->flux) ----------------
__global__ __launch_bounds__(256) void fed_step(const float* __restrict__ src, float* __restrict__ dst){
  __shared__ float Lt[36][37];
  __shared__ float Gt[34][35];
  const int bx = blockIdx.x*32, by = blockIdx.y*32, b = blockIdx.z;
  const float* S = src + (size_t)b*HWp;
  float* D = dst + (size_t)b*HWp;
  const int t = threadIdx.y*32 + threadIdx.x;
  for (int i=t;i<36*36;i+=256){
    int ly=i/36, lx=i-ly*36;
    int gy=by+ly-2, gx=bx+lx-2;
    Lt[ly][lx] = (gy>=0 && gy<Hh && gx>=0 && gx<Ww) ? S[(size_t)gy*Ww+gx] : 0.0f;  // zero-pad for Sobel
  }
  __syncthreads();
  const float k2 = (float)(0.05*0.05);
  for (int i=t;i<34*34;i+=256){
    int ly=i/34, lx=i-ly*34;
    int Ly=ly+1, Lx=lx+1;
    float sx = (-Lt[Ly-1][Lx-1]+Lt[Ly-1][Lx+1]
                -2.0f*Lt[Ly][Lx-1]+2.0f*Lt[Ly][Lx+1]
                -Lt[Ly+1][Lx-1]+Lt[Ly+1][Lx+1])*0.125f;
    float sy = (-Lt[Ly-1][Lx-1]-2.0f*Lt[Ly-1][Lx]-Lt[Ly-1][Lx+1]
                +Lt[Ly+1][Lx-1]+2.0f*Lt[Ly+1][Lx]+Lt[Ly+1][Lx+1])*0.125f;
    Gt[ly][lx] = 1.0f/(1.0f + (sx*sx+sy*sy)/k2);
  }
  __syncthreads();
  for (int r=0;r<4;++r){
    int oy=threadIdx.y + r*8, ox=threadIdx.x;
    int gy=by+oy, gx=bx+ox;
    if (gy>=Hh || gx>=Ww) continue;
    // edge-clamped neighbor coordinates (matches np.pad 'edge')
    int gyn=imax(gy-1,0), gys=imin(gy+1,Hh-1), gxw=imax(gx-1,0), gxe=imin(gx+1,Ww-1);
    float Lc=Lt[oy+2][ox+2];
    float Ln=Lt[gyn-by+2][ox+2];
    float Ls=Lt[gys-by+2][ox+2];
    float Lw=Lt[oy+2][gxw-bx+2];
    float Le=Lt[oy+2][gxe-bx+2];
    float gc=Gt[oy+1][ox+1];
    float gn=Gt[gyn-by+1][ox+1];
    float gs=Gt[gys-by+1][ox+1];
    float gw=Gt[oy+1][gxw-bx+1];
    float ge=Gt[oy+1][gxe-bx+1];
    float flux = 0.5f*((gc+gn)*(Ln-Lc) + (gc+gs)*(Ls-Lc) + (gc+gw)*(Lw-Lc) + (gc+ge)*(Le-Lc));
    D[(size_t)gy*Ww+gx] = Lc + TAUf*flux;
  }
}

// ---------------- Hessian response (Lxx*Lyy - Lxy^2), resp = max(resp, det) ----------------
__global__ __launch_bounds__(256) void response_kernel(const float* __restrict__ src, float* __restrict__ resp){
  __shared__ float Lt[36][37];
  __shared__ float Sx[34][35];
  const int bx = blockIdx.x*32, by = blockIdx.y*32, b = blockIdx.z;
  const float* S = src + (size_t)b*HWp;
  float* R = resp + (size_t)b*HWp;
  const int t = threadIdx.y*32 + threadIdx.x;
  for (int i=t;i<36*36;i+=256){
    int ly=i/36, lx=i-ly*36;
    int gy=by+ly-2, gx=bx+lx-2;
    Lt[ly][lx] = (gy>=0 && gy<Hh && gx>=0 && gx<Ww) ? S[(size_t)gy*Ww+gx] : 0.0f;
  }
  __syncthreads();
  for (int i=t;i<34*34;i+=256){
    int ly=i/34, lx=i-ly*34;
    int gy=by+ly-1, gx=bx+lx-1;
    float v=0.0f;
    if (gy>=0 && gy<Hh && gx>=0 && gx<Ww){   // Sx is zero outside image (zero-pad of first conv's output)
      int Ly=ly+1, Lx=lx+1;
      v = (-Lt[Ly-1][Lx-1]+Lt[Ly-1][Lx+1]
           -2.0f*Lt[Ly][Lx-1]+2.0f*Lt[Ly][Lx+1]
           -Lt[Ly+1][Lx-1]+Lt[Ly+1][Lx+1])*0.125f;
    }
    Sx[ly][lx]=v;
  }
  __syncthreads();
  for (int r=0;r<4;++r){
    int oy=threadIdx.y + r*8, ox=threadIdx.x;
    int gy=by+oy, gx=bx+ox;
    if (gy>=Hh || gx>=Ww) continue;
    int Ly=oy+2, Lx=ox+2;
    float Lxx = Lt[Ly][Lx-1]-2.0f*Lt[Ly][Lx]+Lt[Ly][Lx+1];
    float Lyy = Lt[Ly-1][Lx]-2.0f*Lt[Ly][Lx]+Lt[Ly+1][Lx];
    int Sy=oy+1, Sxi=ox+1;
    float Lxy = (-Sx[Sy-1][Sxi-1]-2.0f*Sx[Sy-1][Sxi]-Sx[Sy-1][Sxi+1]
                 +Sx[Sy+1][Sxi-1]+2.0f*Sx[Sy+1][Sxi]+Sx[Sy+1][Sxi+1])*0.125f;
    float det = Lxx*Lyy - Lxy*Lxy;
    size_t id=(size_t)gy*Ww+gx;
    R[id] = fmaxf(R[id], det);
  }
}

// ---------------- fused: threshold + 5x5 NMS + 7x7 NMS + block compaction ----------------
// One global atomic per block (padded counter stride); wave-ballot compaction in LDS.
__global__ __launch_bounds__(256) void detect_compact(const float* __restrict__ resp,
                                                      u64* __restrict__ lists,
                                                      int* __restrict__ cnt, int segbase){
  const int TS=42;                 // 32 + 2*5 halo (3 for 7x7 + 2 for the 5x5 mask in the halo)
  __shared__ float Tt[TS][TS+1];   // thresholded response
  __shared__ float Ss[38][39];     // 5x5-NMS-masked, halo 3
  __shared__ u64 keys[1024];
  __shared__ int lcnt, gbase;
  const int bx = blockIdx.x*32, by = blockIdx.y*32, b = blockIdx.z;
  const float* S = resp + (size_t)b*HWp;
  const int t = threadIdx.y*32 + threadIdx.x;
  if (t==0) lcnt=0;
  for (int i=t;i<TS*TS;i+=256){
    int ly=i/TS, lx=i-ly*TS;
    int gy=by+ly-5, gx=bx+lx-5;
    float v = (gy>=0 && gy<Hh && gx>=0 && gx<Ww) ? S[(size_t)gy*Ww+gx] : 0.0f;
    Tt[ly][lx] = (v>DET_T) ? v : 0.0f;
  }
  __syncthreads();
  for (int i=t;i<38*38;i+=256){
    int ly=i/38, lx=i-ly*38;
    int ty=ly+2, tx=lx+2;
    float m=0.0f;
    #pragma unroll
    for(int dy=-2;dy<=2;dy++)
      #pragma unroll
      for(int dx=-2;dx<=2;dx++)
        m=fmaxf(m,Tt[ty+dy][tx+dx]);
    float c=Tt[ty][tx];
    Ss[ly][lx]=(c>=m-NMS_EPS)?c:0.0f;
  }
  __syncthreads();
  const int seg=segbase+b;
  for (int r=0;r<4;++r){
    int oy=threadIdx.y + r*8, ox=threadIdx.x;
    int gy=by+oy, gx=bx+ox;
    bool pos=false; u64 key=0;
    if (gy<Hh && gx<Ww){
      float v=Ss[oy+3][ox+3];
      if (v>0.0f){
        float m=0.0f;
        #pragma unroll
        for(int dy=0;dy<7;dy++)
          #pragma unroll
          for(int dx=0;dx<7;dx++)
            m=fmaxf(m,Ss[oy+dy][ox+dx]);
        if (v>=m-NMS_EPS){
          u32 idx=(u32)(gy*Ww+gx);
          key=((u64)__float_as_uint(v)<<32)|(u64)(0xFFFFFFFFu-idx);  // value desc, index asc
          pos=true;
        }
      }
    }
    u64 mask=__ballot(pos);
    if (mask){
      int lane=t&63;
      int leader=__ffsll((long long)mask)-1;
      int base=0;
      if (lane==leader) base=atomicAdd(&lcnt,__popcll(mask));
      base=__shfl(base,leader);
      if (pos){
        int rk=__popcll(mask & ((1ULL<<lane)-1ULL));
        keys[base+rk]=key;
      }
    }
  }
  __syncthreads();
  if (t==0 && lcnt>0) gbase=atomicAdd(&cnt[seg*64], lcnt);   // one atomic per block
  __syncthreads();
  int n=lcnt;
  for (int i=t;i<n;i+=256){
    int p=gbase+i;
    if (p<LISTCAP) lists[(size_t)seg*LISTCAP+p]=keys[i];
  }
}

// ---------------- radix-select top-K: histogram pass ----------------
__global__ void topk_hist(const u64* __restrict__ lists, const int* __restrict__ cnt,
                          const u64* __restrict__ prefix, const int* __restrict__ takeAll,
                          u32* __restrict__ ghist, int round){
  int seg=blockIdx.y;
  if(round>0 && takeAll[seg]) return;
  __shared__ u32 h[256];
  h[threadIdx.x]=0; __syncthreads();
  int n=imin(cnt[seg*64],LISTCAP);
  int shift=56-8*round;
  u64 maskHi=(round==0)?0ULL:(~0ULL<<(shift+8));
  u64 pfx=prefix[seg];
  for(int i=blockIdx.x*256+threadIdx.x;i<n;i+=gridDim.x*256){
    u64 k=lists[(size_t)seg*LISTCAP+i];
    if((k&maskHi)==pfx) atomicAdd(&h[(int)((k>>shift)&255ULL)],1u);
  }
  __syncthreads();
  if(h[threadIdx.x]) atomicAdd(&ghist[seg*256+threadIdx.x],h[threadIdx.x]);
}

// ---------------- radix-select: decide byte, advance state ----------------
__global__ void topk_decide(u32* __restrict__ ghist, const int* __restrict__ cnt,
                            int* __restrict__ krem, int* __restrict__ takeAll,
                            u64* __restrict__ prefix, u64* __restrict__ Tf, int round){
  int t=threadIdx.x;
  if(t<NSEG){
    int seg=t;
    if(round==0){
      krem[seg]=Kk;
      prefix[seg]=0ULL;
      takeAll[seg]=(imin(cnt[seg*64],LISTCAP)<=Kk)?1:0;
    }
    if(takeAll[seg]){
      if(round==7) Tf[seg]=1ULL;   // all keys >= 1 (value>0 => high bits nonzero)
    } else {
      int kr=krem[seg];
      const u32* h=&ghist[seg*256];
      int acc=0; int b=255;
      for(;b>0;--b){ int c2=(int)h[b]; if(acc+c2>=kr) break; acc+=c2; }
      int shift=56-8*round;
      prefix[seg]|=((u64)(u32)b)<<shift;
      krem[seg]=kr-acc;
      if(round==7) Tf[seg]=prefix[seg];
    }
  }
  __syncthreads();
  for(int i=t;i<NSEG*256;i+=blockDim.x) ghist[i]=0u;  // clear for next round
}

// ---------------- gather keys >= threshold (wave-aggregated atomic) ----------------
__global__ void topk_gather(const u64* __restrict__ lists, const int* __restrict__ cnt,
                            const u64* __restrict__ Tf, u64* __restrict__ selbuf, int* __restrict__ selcnt){
  int seg=blockIdx.y;
  int n=imin(cnt[seg*64],LISTCAP);
  u64 T=Tf[seg];
  for(int i0=blockIdx.x*256;i0<n;i0+=gridDim.x*256){
    int i=i0+threadIdx.x;
    bool sel=false; u64 k=0;
    if(i<n){ k=lists[(size_t)seg*LISTCAP+i]; sel=(k>=T); }
    u64 mask=__ballot(sel);
    if(mask){
      int lane=threadIdx.x&63;
      int leader=__ffsll((long long)mask)-1;
      int base=0;
      if(lane==leader) base=atomicAdd(&selcnt[seg*64],__popcll(mask));
      base=__shfl(base,leader);
      if(sel){
        int p=base+__popcll(mask & ((1ULL<<lane)-1ULL));
        if(p<Kk) selbuf[(size_t)seg*Kk+p]=k;
      }
    }
  }
}

// ---------------- sort 1024 keys desc, emit keypoint meta + k1/k2 ----------------
__global__ __launch_bounds__(1024) void finalize_kernel(const u64* __restrict__ selbuf, const int* __restrict__ selcnt,
                                int* __restrict__ kyi, int* __restrict__ kxi, float* __restrict__ kval,
                                float* __restrict__ outp){
  int seg=blockIdx.x, tid=threadIdx.x;
  __shared__ u64 a[1024];
  int n=selcnt[seg*64]; if(n>Kk)n=Kk;
  a[tid]=(tid<n)?selbuf[(size_t)seg*Kk+tid]:0ULL;
  __syncthreads();
  for(int k=2;k<=1024;k<<=1){
    for(int j=k>>1;j>0;j>>=1){
      int ixj=tid^j;
      if(ixj>tid){
        u64 x=a[tid], y=a[ixj];
        bool desc=((tid&k)==0);
        if(desc ? (x<y) : (x>y)){ a[tid]=y; a[ixj]=x; }
      }
      __syncthreads();
    }
  }
  u64 key=a[tid];
  bool val=(key!=0ULL);
  u32 idx=0xFFFFFFFFu-(u32)(key&0xFFFFFFFFULL);
  int y= val ? (int)(idx/Ww) : 0;
  int x= val ? (int)(idx%Ww) : 0;
  int mi=seg*Kk+tid;
  kyi[mi]=y; kxi[mi]=x; kval[mi]= val?1.0f:0.0f;
  int imi=seg>>1, bb=seg&1;
  float* ko=outp + (size_t)imi*(Bb*Kk*2) + ((size_t)bb*Kk+tid)*2;
  ko[0]= val ? (float)y : -1.0f;
  ko[1]= val ? (float)x : -1.0f;
}

// ---------------- Gaussian weights (1D, normalized) ----------------
__global__ void init_weights(float* wn){
  if(threadIdx.x==0 && blockIdx.x==0){
    double w[15]; double S=0.0;
    for(int i=0;i<15;i++){ double c=(double)i-7.0; w[i]=exp(-(c*c)/(2.0*2.5*2.5)); S+=w[i]; }
    for(int i=0;i<15;i++) wn[i]=(float)(w[i]/S);
  }
}

__device__ __forceinline__ float ldz(const float* __restrict__ img,int y,int x){
  return (y>=0&&y<Hh&&x>=0&&x<Ww)?img[(size_t)y*Ww+x]:0.0f;
}

// ---------------- per-keypoint orientation (15x15 Gaussian-weighted Sobel) ----------------
__global__ __launch_bounds__(64) void orient_kernel(const float* __restrict__ img1, const float* __restrict__ img2,
                              const int* __restrict__ kyi, const int* __restrict__ kxi,
                              const float* __restrict__ wn, float* __restrict__ kth){
  int seg=blockIdx.y, ki=blockIdx.x, lane=threadIdx.x;
  __shared__ float w15[15];
  if(lane<15) w15[lane]=wn[lane];
  __syncthreads();
  const float* img=(seg<2?img1:img2)+(size_t)(seg&1)*HWp;
  int mi=seg*Kk+ki;
  int yc=kyi[mi], xc=kxi[mi];
  float ax=0.0f, ay=0.0f;
  for(int tp=lane;tp<225;tp+=64){
    int du=tp/15-7, dv=tp-(tp/15)*15-7;
    int yy=yc+du, xx=xc+dv;
    if(yy<0||yy>=Hh||xx<0||xx>=Ww) continue;   // zero-pad of Sobel output
    float p00=ldz(img,yy-1,xx-1), p01=ldz(img,yy-1,xx), p02=ldz(img,yy-1,xx+1);
    float p10=ldz(img,yy,xx-1),                          p12=ldz(img,yy,xx+1);
    float p20=ldz(img,yy+1,xx-1), p21=ldz(img,yy+1,xx), p22=ldz(img,yy+1,xx+1);
    float sx=(-p00+p02-2.0f*p10+2.0f*p12-p20+p22)*0.125f;
    float sy=(-p00-2.0f*p01-p02+p20+2.0f*p21+p22)*0.125f;
    float wgt=w15[du+7]*w15[dv+7];
    ax=fmaf(wgt,sx,ax); ay=fmaf(wgt,sy,ay);
  }
  for(int o=32;o;o>>=1){ ax+=__shfl_down(ax,o); ay+=__shfl_down(ay,o); }
  if(lane==0) kth[mi]=atan2f(ay,ax);
}

// ---------------- BAD descriptor: box samples + normalize ----------------
__device__ __forceinline__ float boxsum(const float* __restrict__ img, float px, float py, int r){
  float rx=rintf(px), ry=rintf(py);   // round-half-even, then clip (matches jnp.round->clip)
  int xi=(int)fminf(fmaxf(rx,0.0f),(float)(Ww-1));
  int yi=(int)fminf(fmaxf(ry,0.0f),(float)(Hh-1));
  float acc=0.0f;
  for(int dy=-r;dy<=r;dy++){
    int y=yi+dy; if(y<0||y>=Hh) continue;
    const float* rowp=img+(size_t)y*Ww;
    for(int dx=-r;dx<=r;dx++){
      int x=xi+dx; if(x<0||x>=Ww) continue;
      acc+=rowp[x];
    }
  }
  return acc;
}

__global__ __launch_bounds__(256) void bad_kernel(const float* __restrict__ img1, const float* __restrict__ img2,
                           const float* __restrict__ offs, const float* __restrict__ thrv,
                           const int* __restrict__ rad,
                           const int* __restrict__ kyi, const int* __restrict__ kxi,
                           const float* __restrict__ kval, const float* __restrict__ kth,
                           float* __restrict__ d1, float* __restrict__ d2,
                           float* __restrict__ sq1, float* __restrict__ sq2){
  int seg=blockIdx.y, ki=blockIdx.x, p=threadIdx.x;
  const float* img=(seg<2?img1:img2)+(size_t)(seg&1)*HWp;
  int mi=seg*Kk+ki;
  float yc=(float)kyi[mi], xc=(float)kxi[mi];
  float th=kth[mi];
  float c=cosf(th), s=sinf(th);
  float ox1=offs[p*4+0], oy1=offs[p*4+1], ox2=offs[p*4+2], oy2=offs[p*4+3];
  int r=rad[p];
  float w=WR[r];
  float px1=xc+c*ox1-s*oy1, py1=yc+s*ox1+c*oy1;
  float px2=xc+c*ox2-s*oy2, py2=yc+s*ox2+c*oy2;
  float s1=boxsum(img,px1,py1,r)*w;
  float s2=boxsum(img,px2,py2,r)*w;
  float v=(s1-s2-thrv[p])*kval[mi];
  __shared__ float sm[4];
  __shared__ float nsh;
  float t=v*v;
  for(int o=32;o;o>>=1) t+=__shfl_down(t,o);
  if((p&63)==0) sm[p>>6]=t;
  __syncthreads();
  if(p==0) nsh=sqrtf(sm[0]+sm[1]+sm[2]+sm[3]);
  __syncthreads();
  float dv=v/(nsh+1e-8f);
  float* dd=(seg<2?d1:d2);
  dd[((size_t)(seg&1)*Kk+ki)*Pp+p]=dv;
  float t2=dv*dv;
  for(int o=32;o;o>>=1) t2+=__shfl_down(t2,o);
  __syncthreads();
  if((p&63)==0) sm[p>>6]=t2;
  __syncthreads();
  if(p==0){ float* sq=(seg<2?sq1:sq2); sq[(size_t)(seg&1)*Kk+ki]=sm[0]+sm[1]+sm[2]+sm[3]; }
}

// ---------------- pairwise distance -> Z (and transposed copy) ----------------
__global__ __launch_bounds__(256) void dist_kernel(const float* __restrict__ d1, const float* __restrict__ d2,
                            const float* __restrict__ sq1, const float* __restrict__ sq2,
                            float* __restrict__ Zm, float* __restrict__ Zt){
  int b=blockIdx.z;
  int i0=blockIdx.y*16, j0=blockIdx.x*16;
  int ty=threadIdx.y, tx=threadIdx.x;
  __shared__ float A[16][17], Bs[16][17], Ct[16][17];
  const float* D1=d1+(size_t)b*Kk*Pp;
  const float* D2=d2+(size_t)b*Kk*Pp;
  float acc=0.0f;
  for(int p0=0;p0<Pp;p0+=16){
    A[ty][tx]=D1[(size_t)(i0+ty)*Pp+p0+tx];
    Bs[ty][tx]=D2[(size_t)(j0+ty)*Pp+p0+tx];
    __syncthreads();
    #pragma unroll
    for(int kk=0;kk<16;kk++) acc=fmaf(A[ty][kk],Bs[tx][kk],acc);
    __syncthreads();
  }
  float dd=sq1[b*Kk+i0+ty]+sq2[b*Kk+j0+tx]-2.0f*acc;
  float dist=sqrtf(fmaxf(dd,0.0f)+1e-12f);
  Zm[((size_t)b*KP1+(i0+ty))*KP1+(j0+tx)]=-dist;
  Ct[ty][tx]=-dist;
  __syncthreads();
  Zt[((size_t)b*KP1+(j0+ty))*KP1+(i0+tx)]=Ct[tx][ty];
}

__global__ void zborder_kernel(float* __restrict__ Zm, float* __restrict__ Zt){
  int i=blockIdx.x*256+threadIdx.x;
  if(i>=Bb*KP1) return;
  int b=i/KP1, j=i-(i/KP1)*KP1;
  Zm[((size_t)b*KP1+j)*KP1+Kk]=1.0f;
  Zm[((size_t)b*KP1+Kk)*KP1+j]=1.0f;
  Zt[((size_t)b*KP1+j)*KP1+Kk]=1.0f;
  Zt[((size_t)b*KP1+Kk)*KP1+j]=1.0f;
}

// ---------------- Sinkhorn half-iteration: res = log_mu - lse_j(Z[i,:]+o[:]) ----------------
__global__ __launch_bounds__(256) void sink_lse(const float* __restrict__ Zm, const float* __restrict__ ov,
                                                float* __restrict__ res){
  int b=blockIdx.y, i=blockIdx.x;
  const float* row=Zm+((size_t)b*KP1+i)*KP1;
  const float* o=ov+(size_t)b*KP1;
  __shared__ float sm[4];
  __shared__ float Msh;
  int tid=threadIdx.x;
  float m=-3.0e38f;
  for(int j=tid;j<KP1;j+=256) m=fmaxf(m,row[j]+o[j]);
  for(int off2=32;off2;off2>>=1) m=fmaxf(m,__shfl_down(m,off2));
  if((tid&63)==0) sm[tid>>6]=m;
  __syncthreads();
  if(tid==0) Msh=fmaxf(fmaxf(sm[0],sm[1]),fmaxf(sm[2],sm[3]));
  __syncthreads();
  float M=Msh;
  float s=0.0f;
  for(int j=tid;j<KP1;j+=256) s+=expf(row[j]+o[j]-M);
  for(int off2=32;off2;off2>>=1) s+=__shfl_down(s,off2);
  __syncthreads();
  if((tid&63)==0) sm[tid>>6]=s;
  __syncthreads();
  if(tid==0){
    float S=sm[0]+sm[1]+sm[2]+sm[3];
    float lm=(i<Kk)?NORMV:(LOGKV+NORMV);
    res[(size_t)b*KP1+i]=lm-(M+logf(S));
  }
}

// ---------------- final probs = exp(Z+u+v-norm) ----------------
__global__ void probs_kernel(const float* __restrict__ Zm, const float* __restrict__ uu,
                             const float* __restrict__ vv, float* __restrict__ outp){
  size_t i=(size_t)blockIdx.x*256+threadIdx.x;
  const size_t tot=(size_t)Bb*KP1*KP1;
  if(i>=tot) return;
  size_t b=i/((size_t)KP1*KP1);
  size_t rem=i-b*(size_t)KP1*KP1;
  int rr=(int)(rem/KP1), cc=(int)(rem-(size_t)(rem/KP1)*KP1);
  outp[i]=expf(Zm[i]+uu[b*KP1+rr]+vv[b*KP1+cc]-NORMV);
}

extern "C" void kernel_launch(void* const* d_in, const int* in_sizes, int n_in,
                              void* d_out, int out_size, void* d_ws, size_t ws_size,
                              hipStream_t stream) {
  (void)in_sizes; (void)n_in; (void)out_size; (void)ws_size;
  const float* img1=(const float*)d_in[0];
  const float* img2=(const float*)d_in[1];
  const float* offs=(const float*)d_in[2];
  const float* thrv=(const float*)d_in[3];
  const int*   rad =(const int*)d_in[4];
  float* out=(float*)d_out;

  char* wp=(char*)d_ws;
  auto carve=[&](size_t bytes)->char*{ char* p=wp; wp += (bytes+255)&~(size_t)255; return p; };
  float* r0  =(float*)carve(PLn*4);            // L ping / Z
  float* r1  =(float*)carve(PLn*4);            // L pong / Zt
  float* resp=(float*)carve(PLn*4);
  u64*  lists=(u64*)carve((size_t)NSEG*LISTCAP*8);
  char* stateblk = carve(8192);
  int* cnt     =(int*)(stateblk);              // [seg*64], 256B stride per seg
  int* selcnt  =(int*)(stateblk+1024);         // [seg*64]
  int* krem    =(int*)(stateblk+2048);
  int* takeAll =(int*)(stateblk+2112);
  u64* prefix  =(u64*)(stateblk+2176);
  u64* Tf      =(u64*)(stateblk+2240);
  u32* ghist   =(u32*)(stateblk+2304);         // 4KB
  u64* selbuf  =(u64*)carve((size_t)NSEG*Kk*8);
  int* kyi     =(int*)carve((size_t)NSEG*Kk*4);
  int* kxi     =(int*)carve((size_t)NSEG*Kk*4);
  float* kval  =(float*)carve((size_t)NSEG*Kk*4);
  float* kth   =(float*)carve((size_t)NSEG*Kk*4);
  float* d1    =(float*)carve((size_t)Bb*Kk*Pp*4);
  float* d2    =(float*)carve((size_t)Bb*Kk*Pp*4);
  float* sq1   =(float*)carve((size_t)Bb*Kk*4);
  float* sq2   =(float*)carve((size_t)Bb*Kk*4);
  float* uvec  =(float*)carve((size_t)Bb*KP1*4);
  float* vvec  =(float*)carve((size_t)Bb*KP1*4);
  float* wn    =(float*)carve(64);

  hipMemsetAsync(stateblk, 0, 8192, stream);
  init_weights<<<1,32,0,stream>>>(wn);

  dim3 TG(Ww/32, Hh/32, Bb), TB(32,8);
  for(int im=0; im<2; ++im){
    const float* srcimg = (im==0)? img1 : img2;
    hipMemsetAsync(resp, 0, PLn*4, stream);
    hipMemcpyAsync(r0, srcimg, PLn*4, hipMemcpyDeviceToDevice, stream);
    float* cur=r0; float* oth=r1;
    for(int st=1; st<=9; ++st){
      fed_step<<<TG,TB,0,stream>>>(cur, oth);
      float* tp=cur; cur=oth; oth=tp;
      if(st%3==0) response_kernel<<<TG,TB,0,stream>>>(cur, resp);
    }
    detect_compact<<<TG,TB,0,stream>>>(resp, lists, cnt, im*2);
  }

  for(int rd=0; rd<8; ++rd){
    topk_hist<<<dim3(32,NSEG),dim3(256),0,stream>>>(lists, cnt, prefix, takeAll, ghist, rd);
    topk_decide<<<1,256,0,stream>>>(ghist, cnt, krem, takeAll, prefix, Tf, rd);
  }
  topk_gather<<<dim3(64,NSEG),dim3(256),0,stream>>>(lists, cnt, Tf, selbuf, selcnt);
  finalize_kernel<<<NSEG,1024,0,stream>>>(selbuf, selcnt, kyi, kxi, kval, out);
  orient_kernel<<<dim3(Kk,NSEG),dim3(64),0,stream>>>(img1, img2, kyi, kxi, wn, kth);
  bad_kernel<<<dim3(Kk,NSEG),dim3(256),0,stream>>>(img1, img2, offs, thrv, rad,
                                                   kyi, kxi, kval, kth, d1, d2, sq1, sq2);

  float* Zm=r0; float* Zt=r1;   // reuse image buffers
  dist_kernel<<<dim3(64,64,Bb),dim3(16,16),0,stream>>>(d1,d2,sq1,sq2,Zm,Zt);
  zborder_kernel<<<dim3((Bb*KP1+255)/256),dim3(256),0,stream>>>(Zm,Zt);
  hipMemsetAsync(uvec,0,(size_t)Bb*KP1*4,stream);
  hipMemsetAsync(vvec,0,(size_t)Bb*KP1*4,stream);
  for(int it=0; it<20; ++it){
    sink_lse<<<dim3(KP1,Bb),dim3(256),0,stream>>>(Zm, vvec, uvec);
    sink_lse<<<dim3(KP1,Bb),dim3(256),0,stream>>>(Zt, uvec, vvec);
  }
  size_t tot=(size_t)Bb*KP1*KP1;
  probs_kernel<<<dim3((u32)((tot+255)/256)),dim3(256),0,stream>>>(Zm, uvec, vvec, out + (size_t)2*Bb*Kk*2);
}

// Round 3
// 959.580 us; speedup vs baseline: 1.8455x; 1.1041x over previous
//
#include <hip/hip_runtime.h>
#include <math.h>

typedef unsigned long long u64;
typedef unsigned int u32;

#define Hh 960
#define Ww 1280
#define Bb 2
#define Kk 1024
#define Pp 256
#define KP1 1025
#define NSEG 4
#define LISTCAP 131072
#define PR 28
#define PS 57

static const size_t HWp = (size_t)Hh * Ww;   // one plane
static const size_t PLn = HWp * Bb;          // B planes

#define TAUf 0.2f
#define NMS_EPS 1e-7f
#define DET_T 0.001f
#define NORMV (-7.6246189861593985f)   /* -log(2*K) */
#define LOGKV (6.9314718055994531f)    /* log(K) */

__constant__ float WR[6] = {1.0f, 1.0f/9.0f, 1.0f/25.0f, 1.0f/49.0f, 1.0f/81.0f, 1.0f/121.0f};

__device__ __forceinline__ int imin(int a,int b){return a<b?a:b;}
__device__ __forceinline__ int imax(int a,int b){return a>b?a:b;}

// ---------------- FED diffusion step (fused: Sobel->g->flux) ----------------
__global__ __launch_bounds__(256) void fed_step(const float* __restrict__ src, float* __restrict__ dst){
  __shared__ float Lt[36][37];
  __shared__ float Gt[34][35];
  const int bx = blockIdx.x*32, by = blockIdx.y*32, b = blockIdx.z;
  const float* S = src + (size_t)b*HWp;
  float* D = dst + (size_t)b*HWp;
  const int t = threadIdx.y*32 + threadIdx.x;
  for (int i=t;i<36*36;i+=256){
    int ly=i/36, lx=i-ly*36;
    int gy=by+ly-2, gx=bx+lx-2;
    Lt[ly][lx] = (gy>=0 && gy<Hh && gx>=0 && gx<Ww) ? S[(size_t)gy*Ww+gx] : 0.0f;  // zero-pad for Sobel
  }
  __syncthreads();
  const float k2 = (float)(0.05*0.05);
  for (int i=t;i<34*34;i+=256){
    int ly=i/34, lx=i-ly*34;
    int Ly=ly+1, Lx=lx+1;
    float sx = (-Lt[Ly-1][Lx-1]+Lt[Ly-1][Lx+1]
                -2.0f*Lt[Ly][Lx-1]+2.0f*Lt[Ly][Lx+1]
                -Lt[Ly+1][Lx-1]+Lt[Ly+1][Lx+1])*0.125f;
    float sy = (-Lt[Ly-1][Lx-1]-2.0f*Lt[Ly-1][Lx]-Lt[Ly-1][Lx+1]
                +Lt[Ly+1][Lx-1]+2.0f*Lt[Ly+1][Lx]+Lt[Ly+1][Lx+1])*0.125f;
    Gt[ly][lx] = 1.0f/(1.0f + (sx*sx+sy*sy)/k2);
  }
  __syncthreads();
  for (int r=0;r<4;++r){
    int oy=threadIdx.y + r*8, ox=threadIdx.x;
    int gy=by+oy, gx=bx+ox;
    if (gy>=Hh || gx>=Ww) continue;
    // edge-clamped neighbor coordinates (matches np.pad 'edge')
    int gyn=imax(gy-1,0), gys=imin(gy+1,Hh-1), gxw=imax(gx-1,0), gxe=imin(gx+1,Ww-1);
    float Lc=Lt[oy+2][ox+2];
    float Ln=Lt[gyn-by+2][ox+2];
    float Ls=Lt[gys-by+2][ox+2];
    float Lw=Lt[oy+2][gxw-bx+2];
    float Le=Lt[oy+2][gxe-bx+2];
    float gc=Gt[oy+1][ox+1];
    float gn=Gt[gyn-by+1][ox+1];
    float gs=Gt[gys-by+1][ox+1];
    float gw=Gt[oy+1][gxw-bx+1];
    float ge=Gt[oy+1][gxe-bx+1];
    float flux = 0.5f*((gc+gn)*(Ln-Lc) + (gc+gs)*(Ls-Lc) + (gc+gw)*(Lw-Lc) + (gc+ge)*(Le-Lc));
    D[(size_t)gy*Ww+gx] = Lc + TAUf*flux;
  }
}

// ---------------- Hessian response (Lxx*Lyy - Lxy^2), resp = max(resp, det) ----------------
__global__ __launch_bounds__(256) void response_kernel(const float* __restrict__ src, float* __restrict__ resp){
  __shared__ float Lt[36][37];
  __shared__ float Sx[34][35];
  const int bx = blockIdx.x*32, by = blockIdx.y*32, b = blockIdx.z;
  const float* S = src + (size_t)b*HWp;
  float* R = resp + (size_t)b*HWp;
  const int t = threadIdx.y*32 + threadIdx.x;
  for (int i=t;i<36*36;i+=256){
    int ly=i/36, lx=i-ly*36;
    int gy=by+ly-2, gx=bx+lx-2;
    Lt[ly][lx] = (gy>=0 && gy<Hh && gx>=0 && gx<Ww) ? S[(size_t)gy*Ww+gx] : 0.0f;
  }
  __syncthreads();
  for (int i=t;i<34*34;i+=256){
    int ly=i/34, lx=i-ly*34;
    int gy=by+ly-1, gx=bx+lx-1;
    float v=0.0f;
    if (gy>=0 && gy<Hh && gx>=0 && gx<Ww){   // Sx is zero outside image (zero-pad of first conv's output)
      int Ly=ly+1, Lx=lx+1;
      v = (-Lt[Ly-1][Lx-1]+Lt[Ly-1][Lx+1]
           -2.0f*Lt[Ly][Lx-1]+2.0f*Lt[Ly][Lx+1]
           -Lt[Ly+1][Lx-1]+Lt[Ly+1][Lx+1])*0.125f;
    }
    Sx[ly][lx]=v;
  }
  __syncthreads();
  for (int r=0;r<4;++r){
    int oy=threadIdx.y + r*8, ox=threadIdx.x;
    int gy=by+oy, gx=bx+ox;
    if (gy>=Hh || gx>=Ww) continue;
    int Ly=oy+2, Lx=ox+2;
    float Lxx = Lt[Ly][Lx-1]-2.0f*Lt[Ly][Lx]+Lt[Ly][Lx+1];
    float Lyy = Lt[Ly-1][Lx]-2.0f*Lt[Ly][Lx]+Lt[Ly+1][Lx];
    int Sy=oy+1, Sxi=ox+1;
    float Lxy = (-Sx[Sy-1][Sxi-1]-2.0f*Sx[Sy-1][Sxi]-Sx[Sy-1][Sxi+1]
                 +Sx[Sy+1][Sxi-1]+2.0f*Sx[Sy+1][Sxi]+Sx[Sy+1][Sxi+1])*0.125f;
    float det = Lxx*Lyy - Lxy*Lxy;
    size_t id=(size_t)gy*Ww+gx;
    R[id] = fmaxf(R[id], det);
  }
}

// ---------------- fused: threshold + 5x5 NMS + 7x7 NMS + block compaction ----------------
__global__ __launch_bounds__(256) void detect_compact(const float* __restrict__ resp,
                                                      u64* __restrict__ lists,
                                                      int* __restrict__ cnt, int segbase){
  const int TS=42;                 // 32 + 2*5 halo (3 for 7x7 + 2 for the 5x5 mask in the halo)
  __shared__ float Tt[TS][TS+1];   // thresholded response
  __shared__ float Ss[38][39];     // 5x5-NMS-masked, halo 3
  __shared__ u64 keys[1024];
  __shared__ int lcnt, gbase;
  const int bx = blockIdx.x*32, by = blockIdx.y*32, b = blockIdx.z;
  const float* S = resp + (size_t)b*HWp;
  const int t = threadIdx.y*32 + threadIdx.x;
  if (t==0) lcnt=0;
  for (int i=t;i<TS*TS;i+=256){
    int ly=i/TS, lx=i-ly*TS;
    int gy=by+ly-5, gx=bx+lx-5;
    float v = (gy>=0 && gy<Hh && gx>=0 && gx<Ww) ? S[(size_t)gy*Ww+gx] : 0.0f;
    Tt[ly][lx] = (v>DET_T) ? v : 0.0f;
  }
  __syncthreads();
  for (int i=t;i<38*38;i+=256){
    int ly=i/38, lx=i-ly*38;
    int ty=ly+2, tx=lx+2;
    float m=0.0f;
    #pragma unroll
    for(int dy=-2;dy<=2;dy++)
      #pragma unroll
      for(int dx=-2;dx<=2;dx++)
        m=fmaxf(m,Tt[ty+dy][tx+dx]);
    float c=Tt[ty][tx];
    Ss[ly][lx]=(c>=m-NMS_EPS)?c:0.0f;
  }
  __syncthreads();
  const int seg=segbase+b;
  for (int r=0;r<4;++r){
    int oy=threadIdx.y + r*8, ox=threadIdx.x;
    int gy=by+oy, gx=bx+ox;
    bool pos=false; u64 key=0;
    if (gy<Hh && gx<Ww){
      float v=Ss[oy+3][ox+3];
      if (v>0.0f){
        float m=0.0f;
        #pragma unroll
        for(int dy=0;dy<7;dy++)
          #pragma unroll
          for(int dx=0;dx<7;dx++)
            m=fmaxf(m,Ss[oy+dy][ox+dx]);
        if (v>=m-NMS_EPS){
          u32 idx=(u32)(gy*Ww+gx);
          key=((u64)__float_as_uint(v)<<32)|(u64)(0xFFFFFFFFu-idx);  // value desc, index asc
          pos=true;
        }
      }
    }
    u64 mask=__ballot(pos);
    if (mask){
      int lane=t&63;
      int leader=__ffsll((long long)mask)-1;
      int base=0;
      if (lane==leader) base=atomicAdd(&lcnt,__popcll(mask));
      base=__shfl(base,leader);
      if (pos){
        int rk=__popcll(mask & ((1ULL<<lane)-1ULL));
        keys[base+rk]=key;
      }
    }
  }
  __syncthreads();
  if (t==0 && lcnt>0) gbase=atomicAdd(&cnt[seg*64], lcnt);   // one atomic per block
  __syncthreads();
  int n=lcnt;
  for (int i=t;i<n;i+=256){
    int p=gbase+i;
    if (p<LISTCAP) lists[(size_t)seg*LISTCAP+p]=keys[i];
  }
}

// ---------------- radix-select top-K: histogram pass ----------------
__global__ void topk_hist(const u64* __restrict__ lists, const int* __restrict__ cnt,
                          const u64* __restrict__ prefix, const int* __restrict__ takeAll,
                          u32* __restrict__ ghist, int round){
  int seg=blockIdx.y;
  if(round>0 && takeAll[seg]) return;
  __shared__ u32 h[256];
  h[threadIdx.x]=0; __syncthreads();
  int n=imin(cnt[seg*64],LISTCAP);
  int shift=56-8*round;
  u64 maskHi=(round==0)?0ULL:(~0ULL<<(shift+8));
  u64 pfx=prefix[seg];
  for(int i=blockIdx.x*256+threadIdx.x;i<n;i+=gridDim.x*256){
    u64 k=lists[(size_t)seg*LISTCAP+i];
    if((k&maskHi)==pfx) atomicAdd(&h[(int)((k>>shift)&255ULL)],1u);
  }
  __syncthreads();
  if(h[threadIdx.x]) atomicAdd(&ghist[seg*256+threadIdx.x],h[threadIdx.x]);
}

// ---------------- radix-select: decide byte, advance state ----------------
__global__ void topk_decide(u32* __restrict__ ghist, const int* __restrict__ cnt,
                            int* __restrict__ krem, int* __restrict__ takeAll,
                            u64* __restrict__ prefix, u64* __restrict__ Tf, int round){
  int t=threadIdx.x;
  if(t<NSEG){
    int seg=t;
    if(round==0){
      krem[seg]=Kk;
      prefix[seg]=0ULL;
      takeAll[seg]=(imin(cnt[seg*64],LISTCAP)<=Kk)?1:0;
    }
    if(takeAll[seg]){
      if(round==7) Tf[seg]=1ULL;   // all keys >= 1 (value>0 => high bits nonzero)
    } else {
      int kr=krem[seg];
      const u32* h=&ghist[seg*256];
      int acc=0; int b=255;
      for(;b>0;--b){ int c2=(int)h[b]; if(acc+c2>=kr) break; acc+=c2; }
      int shift=56-8*round;
      prefix[seg]|=((u64)(u32)b)<<shift;
      krem[seg]=kr-acc;
      if(round==7) Tf[seg]=prefix[seg];
    }
  }
  __syncthreads();
  for(int i=t;i<NSEG*256;i+=blockDim.x) ghist[i]=0u;  // clear for next round
}

// ---------------- gather keys >= threshold (wave-aggregated atomic) ----------------
__global__ void topk_gather(const u64* __restrict__ lists, const int* __restrict__ cnt,
                            const u64* __restrict__ Tf, u64* __restrict__ selbuf, int* __restrict__ selcnt){
  int seg=blockIdx.y;
  int n=imin(cnt[seg*64],LISTCAP);
  u64 T=Tf[seg];
  for(int i0=blockIdx.x*256;i0<n;i0+=gridDim.x*256){
    int i=i0+threadIdx.x;
    bool sel=false; u64 k=0;
    if(i<n){ k=lists[(size_t)seg*LISTCAP+i]; sel=(k>=T); }
    u64 mask=__ballot(sel);
    if(mask){
      int lane=threadIdx.x&63;
      int leader=__ffsll((long long)mask)-1;
      int base=0;
      if(lane==leader) base=atomicAdd(&selcnt[seg*64],__popcll(mask));
      base=__shfl(base,leader);
      if(sel){
        int p=base+__popcll(mask & ((1ULL<<lane)-1ULL));
        if(p<Kk) selbuf[(size_t)seg*Kk+p]=k;
      }
    }
  }
}

// ---------------- sort 1024 keys desc, emit keypoint meta + k1/k2 ----------------
__global__ __launch_bounds__(1024) void finalize_kernel(const u64* __restrict__ selbuf, const int* __restrict__ selcnt,
                                int* __restrict__ kyi, int* __restrict__ kxi, float* __restrict__ kval,
                                float* __restrict__ outp){
  int seg=blockIdx.x, tid=threadIdx.x;
  __shared__ u64 a[1024];
  int n=selcnt[seg*64]; if(n>Kk)n=Kk;
  a[tid]=(tid<n)?selbuf[(size_t)seg*Kk+tid]:0ULL;
  __syncthreads();
  for(int k=2;k<=1024;k<<=1){
    for(int j=k>>1;j>0;j>>=1){
      int ixj=tid^j;
      if(ixj>tid){
        u64 x=a[tid], y=a[ixj];
        bool desc=((tid&k)==0);
        if(desc ? (x<y) : (x>y)){ a[tid]=y; a[ixj]=x; }
      }
      __syncthreads();
    }
  }
  u64 key=a[tid];
  bool val=(key!=0ULL);
  u32 idx=0xFFFFFFFFu-(u32)(key&0xFFFFFFFFULL);
  int y= val ? (int)(idx/Ww) : 0;
  int x= val ? (int)(idx%Ww) : 0;
  int mi=seg*Kk+tid;
  kyi[mi]=y; kxi[mi]=x; kval[mi]= val?1.0f:0.0f;
  int imi=seg>>1, bb=seg&1;
  float* ko=outp + (size_t)imi*(Bb*Kk*2) + ((size_t)bb*Kk+tid)*2;
  ko[0]= val ? (float)y : -1.0f;
  ko[1]= val ? (float)x : -1.0f;
}

// ---------------- Gaussian weights (1D, normalized) ----------------
__global__ void init_weights(float* wn){
  if(threadIdx.x==0 && blockIdx.x==0){
    double w[15]; double S=0.0;
    for(int i=0;i<15;i++){ double c=(double)i-7.0; w[i]=exp(-(c*c)/(2.0*2.5*2.5)); S+=w[i]; }
    for(int i=0;i<15;i++) wn[i]=(float)(w[i]/S);
  }
}

__device__ __forceinline__ float ldz(const float* __restrict__ img,int y,int x){
  return (y>=0&&y<Hh&&x>=0&&x<Ww)?img[(size_t)y*Ww+x]:0.0f;
}

// ---------------- per-keypoint orientation (15x15 Gaussian-weighted Sobel) ----------------
__global__ __launch_bounds__(64) void orient_kernel(const float* __restrict__ img1, const float* __restrict__ img2,
                              const int* __restrict__ kyi, const int* __restrict__ kxi,
                              const float* __restrict__ wn, float* __restrict__ kth){
  int seg=blockIdx.y, ki=blockIdx.x, lane=threadIdx.x;
  __shared__ float w15[15];
  if(lane<15) w15[lane]=wn[lane];
  __syncthreads();
  const float* img=(seg<2?img1:img2)+(size_t)(seg&1)*HWp;
  int mi=seg*Kk+ki;
  int yc=kyi[mi], xc=kxi[mi];
  float ax=0.0f, ay=0.0f;
  for(int tp=lane;tp<225;tp+=64){
    int du=tp/15-7, dv=tp-(tp/15)*15-7;
    int yy=yc+du, xx=xc+dv;
    if(yy<0||yy>=Hh||xx<0||xx>=Ww) continue;   // zero-pad of Sobel output
    float p00=ldz(img,yy-1,xx-1), p01=ldz(img,yy-1,xx), p02=ldz(img,yy-1,xx+1);
    float p10=ldz(img,yy,xx-1),                          p12=ldz(img,yy,xx+1);
    float p20=ldz(img,yy+1,xx-1), p21=ldz(img,yy+1,xx), p22=ldz(img,yy+1,xx+1);
    float sx=(-p00+p02-2.0f*p10+2.0f*p12-p20+p22)*0.125f;
    float sy=(-p00-2.0f*p01-p02+p20+2.0f*p21+p22)*0.125f;
    float wgt=w15[du+7]*w15[dv+7];
    ax=fmaf(wgt,sx,ax); ay=fmaf(wgt,sy,ay);
  }
  for(int o=32;o;o>>=1){ ax+=__shfl_down(ax,o); ay+=__shfl_down(ay,o); }
  if(lane==0) kth[mi]=atan2f(ay,ax);
}

// ---------------- BAD descriptor: LDS-staged 57x57 patch + box samples + normalize ----------------
__global__ __launch_bounds__(256) void bad_kernel(const float* __restrict__ img1, const float* __restrict__ img2,
                           const float* __restrict__ offs, const float* __restrict__ thrv,
                           const int* __restrict__ rad,
                           const int* __restrict__ kyi, const int* __restrict__ kxi,
                           const float* __restrict__ kval, const float* __restrict__ kth,
                           float* __restrict__ d1, float* __restrict__ d2,
                           float* __restrict__ sq1, float* __restrict__ sq2){
  __shared__ float patch[PS][PS+1];
  __shared__ float sm[4];
  __shared__ float nsh;
  int seg=blockIdx.y, ki=blockIdx.x, p=threadIdx.x;
  const float* img=(seg<2?img1:img2)+(size_t)(seg&1)*HWp;
  int mi=seg*Kk+ki;
  int yci=kyi[mi], xci=kxi[mi];
  // stage the 57x57 neighborhood (zero outside image; "skip" == "+0.0f")
  for (int i=p;i<PS*PS;i+=256){
    int ly=i/PS, lx=i-ly*PS;
    int gy=yci-PR+ly, gx=xci-PR+lx;
    patch[ly][lx]=(gy>=0&&gy<Hh&&gx>=0&&gx<Ww)?img[(size_t)gy*Ww+gx]:0.0f;
  }
  __syncthreads();
  float yc=(float)yci, xc=(float)xci;
  float th=kth[mi];
  float c=cosf(th), s=sinf(th);
  float ox1=offs[p*4+0], oy1=offs[p*4+1], ox2=offs[p*4+2], oy2=offs[p*4+3];
  int r=rad[p];
  float w=WR[r];
  float px1=xc+c*ox1-s*oy1, py1=yc+s*ox1+c*oy1;
  float px2=xc+c*ox2-s*oy2, py2=yc+s*ox2+c*oy2;
  // local boxsum from LDS (same tap order & arithmetic as global version)
  auto boxl=[&](float px,float py,int r_)->float{
    float rx=rintf(px), ry=rintf(py);
    int xi=(int)fminf(fmaxf(rx,0.0f),(float)(Ww-1));
    int yi=(int)fminf(fmaxf(ry,0.0f),(float)(Hh-1));
    int lx=xi-(xci-PR), ly=yi-(yci-PR);   // guaranteed in [5,51]
    float acc=0.0f;
    for(int dy=-r_;dy<=r_;dy++){
      const float* rowp=&patch[ly+dy][lx];
      for(int dx=-r_;dx<=r_;dx++) acc+=rowp[dx];
    }
    return acc;
  };
  float s1=boxl(px1,py1,r)*w;
  float s2=boxl(px2,py2,r)*w;
  float v=(s1-s2-thrv[p])*kval[mi];
  float t=v*v;
  for(int o=32;o;o>>=1) t+=__shfl_down(t,o);
  if((p&63)==0) sm[p>>6]=t;
  __syncthreads();
  if(p==0) nsh=sqrtf(sm[0]+sm[1]+sm[2]+sm[3]);
  __syncthreads();
  float dv=v/(nsh+1e-8f);
  float* dd=(seg<2?d1:d2);
  dd[((size_t)(seg&1)*Kk+ki)*Pp+p]=dv;
  float t2=dv*dv;
  for(int o=32;o;o>>=1) t2+=__shfl_down(t2,o);
  __syncthreads();
  if((p&63)==0) sm[p>>6]=t2;
  __syncthreads();
  if(p==0){ float* sq=(seg<2?sq1:sq2); sq[(size_t)(seg&1)*Kk+ki]=sm[0]+sm[1]+sm[2]+sm[3]; }
}

// ---------------- pairwise distance -> Z (and transposed copy) ----------------
__global__ __launch_bounds__(256) void dist_kernel(const float* __restrict__ d1, const float* __restrict__ d2,
                            const float* __restrict__ sq1, const float* __restrict__ sq2,
                            float* __restrict__ Zm, float* __restrict__ Zt){
  int b=blockIdx.z;
  int i0=blockIdx.y*16, j0=blockIdx.x*16;
  int ty=threadIdx.y, tx=threadIdx.x;
  __shared__ float A[16][17], Bs[16][17], Ct[16][17];
  const float* D1=d1+(size_t)b*Kk*Pp;
  const float* D2=d2+(size_t)b*Kk*Pp;
  float acc=0.0f;
  for(int p0=0;p0<Pp;p0+=16){
    A[ty][tx]=D1[(size_t)(i0+ty)*Pp+p0+tx];
    Bs[ty][tx]=D2[(size_t)(j0+ty)*Pp+p0+tx];
    __syncthreads();
    #pragma unroll
    for(int kk=0;kk<16;kk++) acc=fmaf(A[ty][kk],Bs[tx][kk],acc);
    __syncthreads();
  }
  float dd=sq1[b*Kk+i0+ty]+sq2[b*Kk+j0+tx]-2.0f*acc;
  float dist=sqrtf(fmaxf(dd,0.0f)+1e-12f);
  Zm[((size_t)b*KP1+(i0+ty))*KP1+(j0+tx)]=-dist;
  Ct[ty][tx]=-dist;
  __syncthreads();
  Zt[((size_t)b*KP1+(j0+ty))*KP1+(i0+tx)]=Ct[tx][ty];
}

__global__ void zborder_kernel(float* __restrict__ Zm, float* __restrict__ Zt){
  int i=blockIdx.x*256+threadIdx.x;
  if(i>=Bb*KP1) return;
  int b=i/KP1, j=i-(i/KP1)*KP1;
  Zm[((size_t)b*KP1+j)*KP1+Kk]=1.0f;
  Zm[((size_t)b*KP1+Kk)*KP1+j]=1.0f;
  Zt[((size_t)b*KP1+j)*KP1+Kk]=1.0f;
  Zt[((size_t)b*KP1+Kk)*KP1+j]=1.0f;
}

// ---------------- Sinkhorn half-iteration: res = log_mu - lse_j(Z[i,:]+o[:]) ----------------
__global__ __launch_bounds__(256) void sink_lse(const float* __restrict__ Zm, const float* __restrict__ ov,
                                                float* __restrict__ res){
  int b=blockIdx.y, i=blockIdx.x;
  const float* row=Zm+((size_t)b*KP1+i)*KP1;
  const float* o=ov+(size_t)b*KP1;
  __shared__ float sm[4];
  __shared__ float Msh;
  int tid=threadIdx.x;
  float m=-3.0e38f;
  for(int j=tid;j<KP1;j+=256) m=fmaxf(m,row[j]+o[j]);
  for(int off2=32;off2;off2>>=1) m=fmaxf(m,__shfl_down(m,off2));
  if((tid&63)==0) sm[tid>>6]=m;
  __syncthreads();
  if(tid==0) Msh=fmaxf(fmaxf(sm[0],sm[1]),fmaxf(sm[2],sm[3]));
  __syncthreads();
  float M=Msh;
  float s=0.0f;
  for(int j=tid;j<KP1;j+=256) s+=expf(row[j]+o[j]-M);
  for(int off2=32;off2;off2>>=1) s+=__shfl_down(s,off2);
  __syncthreads();
  if((tid&63)==0) sm[tid>>6]=s;
  __syncthreads();
  if(tid==0){
    float S=sm[0]+sm[1]+sm[2]+sm[3];
    float lm=(i<Kk)?NORMV:(LOGKV+NORMV);
    res[(size_t)b*KP1+i]=lm-(M+logf(S));
  }
}

// ---------------- final probs = exp(Z+u+v-norm) ----------------
__global__ void probs_kernel(const float* __restrict__ Zm, const float* __restrict__ uu,
                             const float* __restrict__ vv, float* __restrict__ outp){
  size_t i=(size_t)blockIdx.x*256+threadIdx.x;
  const size_t tot=(size_t)Bb*KP1*KP1;
  if(i>=tot) return;
  size_t b=i/((size_t)KP1*KP1);
  size_t rem=i-b*(size_t)KP1*KP1;
  int rr=(int)(rem/KP1), cc=(int)(rem-(size_t)(rem/KP1)*KP1);
  outp[i]=expf(Zm[i]+uu[b*KP1+rr]+vv[b*KP1+cc]-NORMV);
}

extern "C" void kernel_launch(void* const* d_in, const int* in_sizes, int n_in,
                              void* d_out, int out_size, void* d_ws, size_t ws_size,
                              hipStream_t stream) {
  (void)in_sizes; (void)n_in; (void)out_size; (void)ws_size;
  const float* img1=(const float*)d_in[0];
  const float* img2=(const float*)d_in[1];
  const float* offs=(const float*)d_in[2];
  const float* thrv=(const float*)d_in[3];
  const int*   rad =(const int*)d_in[4];
  float* out=(float*)d_out;

  char* wp=(char*)d_ws;
  auto carve=[&](size_t bytes)->char*{ char* p=wp; wp += (bytes+255)&~(size_t)255; return p; };
  float* r0  =(float*)carve(PLn*4);            // L ping / Z
  float* r1  =(float*)carve(PLn*4);            // L pong / Zt
  float* resp=(float*)carve(PLn*4);
  u64*  lists=(u64*)carve((size_t)NSEG*LISTCAP*8);
  char* stateblk = carve(8192);
  int* cnt     =(int*)(stateblk);              // [seg*64], 256B stride per seg
  int* selcnt  =(int*)(stateblk+1024);         // [seg*64]
  int* krem    =(int*)(stateblk+2048);
  int* takeAll =(int*)(stateblk+2112);
  u64* prefix  =(u64*)(stateblk+2176);
  u64* Tf      =(u64*)(stateblk+2240);
  u32* ghist   =(u32*)(stateblk+2304);         // 4KB
  u64* selbuf  =(u64*)carve((size_t)NSEG*Kk*8);
  int* kyi     =(int*)carve((size_t)NSEG*Kk*4);
  int* kxi     =(int*)carve((size_t)NSEG*Kk*4);
  float* kval  =(float*)carve((size_t)NSEG*Kk*4);
  float* kth   =(float*)carve((size_t)NSEG*Kk*4);
  float* d1    =(float*)carve((size_t)Bb*Kk*Pp*4);
  float* d2    =(float*)carve((size_t)Bb*Kk*Pp*4);
  float* sq1   =(float*)carve((size_t)Bb*Kk*4);
  float* sq2   =(float*)carve((size_t)Bb*Kk*4);
  float* uvec  =(float*)carve((size_t)Bb*KP1*4);
  float* vvec  =(float*)carve((size_t)Bb*KP1*4);
  float* wn    =(float*)carve(64);

  hipMemsetAsync(stateblk, 0, 8192, stream);
  init_weights<<<1,32,0,stream>>>(wn);

  dim3 TG(Ww/32, Hh/32, Bb), TB(32,8);
  for(int im=0; im<2; ++im){
    const float* srcimg = (im==0)? img1 : img2;
    hipMemsetAsync(resp, 0, PLn*4, stream);
    hipMemcpyAsync(r0, srcimg, PLn*4, hipMemcpyDeviceToDevice, stream);
    float* cur=r0; float* oth=r1;
    for(int st=1; st<=9; ++st){
      fed_step<<<TG,TB,0,stream>>>(cur, oth);
      float* tp=cur; cur=oth; oth=tp;
      if(st%3==0) response_kernel<<<TG,TB,0,stream>>>(cur, resp);
    }
    detect_compact<<<TG,TB,0,stream>>>(resp, lists, cnt, im*2);
  }

  for(int rd=0; rd<8; ++rd){
    topk_hist<<<dim3(32,NSEG),dim3(256),0,stream>>>(lists, cnt, prefix, takeAll, ghist, rd);
    topk_decide<<<1,256,0,stream>>>(ghist, cnt, krem, takeAll, prefix, Tf, rd);
  }
  topk_gather<<<dim3(64,NSEG),dim3(256),0,stream>>>(lists, cnt, Tf, selbuf, selcnt);
  finalize_kernel<<<NSEG,1024,0,stream>>>(selbuf, selcnt, kyi, kxi, kval, out);
  orient_kernel<<<dim3(Kk,NSEG),dim3(64),0,stream>>>(img1, img2, kyi, kxi, wn, kth);
  bad_kernel<<<dim3(Kk,NSEG),dim3(256),0,stream>>>(img1, img2, offs, thrv, rad,
                                                   kyi, kxi, kval, kth, d1, d2, sq1, sq2);

  float* Zm=r0; float* Zt=r1;   // reuse image buffers
  dist_kernel<<<dim3(64,64,Bb),dim3(16,16),0,stream>>>(d1,d2,sq1,sq2,Zm,Zt);
  zborder_kernel<<<dim3((Bb*KP1+255)/256),dim3(256),0,stream>>>(Zm,Zt);
  hipMemsetAsync(uvec,0,(size_t)Bb*KP1*4,stream);
  hipMemsetAsync(vvec,0,(size_t)Bb*KP1*4,stream);
  for(int it=0; it<20; ++it){
    sink_lse<<<dim3(KP1,Bb),dim3(256),0,stream>>>(Zm, vvec, uvec);
    sink_lse<<<dim3(KP1,Bb),dim3(256),0,stream>>>(Zt, uvec, vvec);
  }
  size_t tot=(size_t)Bb*KP1*KP1;
  probs_kernel<<<dim3((u32)((tot+255)/256)),dim3(256),0,stream>>>(Zm, uvec, vvec, out + (size_t)2*Bb*Kk*2);
}